// Round 1
// baseline (327.904 us; speedup 1.0000x reference)
//
#include <hip/hip_runtime.h>
#include <math.h>

#define N_RES 512
#define NPROJ 1152
#define LSTR  520   // 512 + 8 pad: breaks stride-512 LDS bank aliasing

// ---------------------------------------------------------------------------
// Kernel 1: all input projections as one tiled GEMM.
// proj row layout (per residue): [0,192)=q (h*16+c), [192,576)=kv (h*32 + {c|16+c}),
// [576,720)=qp raw (y*48+p), [720,1152)=kvp raw (y*144+p)
// grid: (32 i-tiles of 16 rows) x (24 col-chunks of 48), 768 threads
// ---------------------------------------------------------------------------
__global__ __launch_bounds__(768) void k_proj(
    const float* __restrict__ s,
    const float* __restrict__ Wq,  const float* __restrict__ bq,
    const float* __restrict__ Wkv, const float* __restrict__ bkv,
    const float* __restrict__ Wqp, const float* __restrict__ bqp,
    const float* __restrict__ Wkvp,const float* __restrict__ bkvp,
    float* __restrict__ proj)
{
    const int it = blockIdx.x;   // 0..31
    const int ch = blockIdx.y;   // 0..23
    const int t  = threadIdx.x;
    const int r  = t / 48;       // 0..15
    const int c  = t % 48;
    __shared__ float s_lds[16 * 384];
    __shared__ float w_lds[32 * 48];

    for (int idx = t; idx < 16 * 384; idx += 768) {
        int rr = idx / 384, kk = idx % 384;
        s_lds[idx] = s[(size_t)(it * 16 + rr) * 384 + kk];
    }

    const int col = ch * 48;
    const float* W; const float* bv; int wN, wc;
    if (col < 192)      { W = Wq;   bv = bq;   wN = 192; wc = col; }
    else if (col < 576) { W = Wkv;  bv = bkv;  wN = 384; wc = col - 192; }
    else if (col < 720) { W = Wqp;  bv = bqp;  wN = 144; wc = col - 576; }
    else                { W = Wkvp; bv = bkvp; wN = 432; wc = col - 720; }

    float acc = 0.f;
    for (int k0 = 0; k0 < 384; k0 += 32) {
        __syncthreads();
        for (int idx = t; idx < 32 * 48; idx += 768) {
            int kk = idx / 48, cc = idx % 48;
            w_lds[idx] = W[(size_t)(k0 + kk) * wN + wc + cc];
        }
        __syncthreads();
        #pragma unroll
        for (int kk = 0; kk < 32; ++kk)
            acc = fmaf(s_lds[r * 384 + k0 + kk], w_lds[kk * 48 + c], acc);
    }
    proj[(size_t)(it * 16 + r) * NPROJ + col + c] = acc + bv[wc + c];
}

// ---------------------------------------------------------------------------
// Kernel 2: rotate/translate qp & kvp into global frame.
// qp_g: [i][h*4+p][3], kp_g: [i][h*4+p][3], vp_g: [i][h*8+p][3]
// ---------------------------------------------------------------------------
__global__ __launch_bounds__(192) void k_rot(
    const float* __restrict__ proj, const float* __restrict__ rots,
    const float* __restrict__ trans,
    float* __restrict__ qp_g, float* __restrict__ kp_g, float* __restrict__ vp_g)
{
    const int i = blockIdx.x;
    const int t = threadIdx.x;
    const float* R = rots  + (size_t)i * 9;
    const float* T = trans + (size_t)i * 3;
    const float* row = proj + (size_t)i * NPROJ;
    const float r00=R[0],r01=R[1],r02=R[2],r10=R[3],r11=R[4],r12=R[5],r20=R[6],r21=R[7],r22=R[8];
    const float t0=T[0], t1=T[1], t2=T[2];
    if (t < 48) {
        const int p = t;   // = h*4 + pq
        const float v0 = row[576 + p], v1 = row[576 + 48 + p], v2 = row[576 + 96 + p];
        float* dst = qp_g + (size_t)i*144 + p*3;
        dst[0] = r00*v0 + r01*v1 + r02*v2 + t0;
        dst[1] = r10*v0 + r11*v1 + r12*v2 + t1;
        dst[2] = r20*v0 + r21*v1 + r22*v2 + t2;
    } else {
        const int p = t - 48;  // 0..143 = h*12 + pp
        const float v0 = row[720 + p], v1 = row[720 + 144 + p], v2 = row[720 + 288 + p];
        const float o0 = r00*v0 + r01*v1 + r02*v2 + t0;
        const float o1 = r10*v0 + r11*v1 + r12*v2 + t1;
        const float o2 = r20*v0 + r21*v1 + r22*v2 + t2;
        const int h = p / 12, pp = p % 12;
        if (pp < 4) {
            float* dst = kp_g + (size_t)i*144 + (h*4+pp)*3;
            dst[0]=o0; dst[1]=o1; dst[2]=o2;
        } else {
            float* dst = vp_g + (size_t)i*288 + (h*8+(pp-4))*3;
            dst[0]=o0; dst[1]=o1; dst[2]=o2;
        }
    }
}

// ---------------------------------------------------------------------------
// Kernel 3: fused attention. One block per residue i, 256 threads (4 waves).
// Phase 1: logits for all (h,j). Phase 2: softmax. Phase 3: o / o_pt / o_pair.
// Epilogue: inverse transform + norm, write concat row (2112 floats).
// cat layout: [0,192)=o, [192+96x, ...)=o_pt x-comp (x=0..2), [480,576)=norm,
// [576,2112)=o_pair (h*128+c)
// ---------------------------------------------------------------------------
__global__ __launch_bounds__(256) void k_attn(
    const float* __restrict__ proj, const float* __restrict__ z,
    const float* __restrict__ rots, const float* __restrict__ trans,
    const float* __restrict__ mask,
    const float* __restrict__ Wb,  const float* __restrict__ bb,
    const float* __restrict__ head_w,
    const float* __restrict__ qp_g, const float* __restrict__ kp_g,
    const float* __restrict__ vp_g,
    float* __restrict__ cat)
{
    const int i = blockIdx.x;
    const int t = threadIdx.x;
    __shared__ float l_lds[12 * LSTR];
    __shared__ float opt_raw[288];

    const float SC_QK = 0.14433756729740643f;  // sqrt(1/48)
    const float SC_B  = 0.57735026918962576f;  // sqrt(1/3)
    const float SC_HW = 0.13608276348795434f;  // sqrt(1/54)

    const float* qr  = proj + (size_t)i * NPROJ;    // q at cols [0,192)
    const float* qpr = qp_g + (size_t)i * 144;
    const float  mi  = mask[i];

    float hw[12], bbr[12];
    #pragma unroll
    for (int h = 0; h < 12; ++h) {
        hw[h]  = log1pf(expf(head_w[h])) * SC_HW;   // softplus * sqrt(1/54)
        bbr[h] = bb[h];
    }

    // ---- phase 1: logits ----
    for (int j = t; j < N_RES; j += 256) {
        float bias[12];
        #pragma unroll
        for (int h = 0; h < 12; ++h) bias[h] = bbr[h];
        const float* zr = z + ((size_t)i * N_RES + j) * 128;
        for (int c = 0; c < 128; c += 4) {
            const float4 zv = *(const float4*)(zr + c);
            #pragma unroll
            for (int h = 0; h < 12; ++h) {   // Wb reads are wave-uniform -> scalar loads
                bias[h] = fmaf(zv.x, Wb[(c+0)*12 + h], bias[h]);
                bias[h] = fmaf(zv.y, Wb[(c+1)*12 + h], bias[h]);
                bias[h] = fmaf(zv.z, Wb[(c+2)*12 + h], bias[h]);
                bias[h] = fmaf(zv.w, Wb[(c+3)*12 + h], bias[h]);
            }
        }
        const float* kr  = proj + (size_t)j * NPROJ + 192;
        const float* kpr = kp_g + (size_t)j * 144;
        const float mterm = 100000.0f * (mi * mask[j] - 1.0f);
        #pragma unroll
        for (int h = 0; h < 12; ++h) {
            float qk = 0.f;
            #pragma unroll
            for (int c = 0; c < 16; c += 4) {
                const float4 k4 = *(const float4*)(kr + h*32 + c);
                qk = fmaf(qr[h*16+c+0], k4.x, qk);
                qk = fmaf(qr[h*16+c+1], k4.y, qk);
                qk = fmaf(qr[h*16+c+2], k4.z, qk);
                qk = fmaf(qr[h*16+c+3], k4.w, qk);
            }
            float s2 = 0.f;
            #pragma unroll
            for (int p = 0; p < 4; ++p) {
                const float dx = qpr[(h*4+p)*3+0] - kpr[(h*4+p)*3+0];
                const float dy = qpr[(h*4+p)*3+1] - kpr[(h*4+p)*3+1];
                const float dz = qpr[(h*4+p)*3+2] - kpr[(h*4+p)*3+2];
                s2 += dx*dx + dy*dy + dz*dz;
            }
            l_lds[h*LSTR + j] = fmaf(qk, SC_QK,
                                 fmaf(bias[h], SC_B,
                                  fmaf(-0.5f*hw[h], s2, mterm)));
        }
    }
    __syncthreads();

    // ---- phase 2: softmax (wave w handles heads 3w..3w+2) ----
    {
        const int wv = t >> 6, lane = t & 63;
        for (int h = wv*3; h < wv*3+3; ++h) {
            float e[8];
            float m = -3.4e38f;
            #pragma unroll
            for (int u = 0; u < 8; ++u) { e[u] = l_lds[h*LSTR + lane + u*64]; m = fmaxf(m, e[u]); }
            #pragma unroll
            for (int d = 1; d < 64; d <<= 1) m = fmaxf(m, __shfl_xor(m, d, 64));
            float ssum = 0.f;
            #pragma unroll
            for (int u = 0; u < 8; ++u) { e[u] = expf(e[u] - m); ssum += e[u]; }
            #pragma unroll
            for (int d = 1; d < 64; d <<= 1) ssum += __shfl_xor(ssum, d, 64);
            const float inv = 1.f / ssum;
            #pragma unroll
            for (int u = 0; u < 8; ++u) l_lds[h*LSTR + lane + u*64] = e[u] * inv;
        }
    }
    __syncthreads();

    // ---- phase 3: weighted sums over j ----
    // o_pair: thread owns (c = t&127, heads hgrp*6..hgrp*6+5)
    // o/o_pt: out idx0 = t (t<192 -> o[h=t/16][c=t%16], else vp idx t-192),
    //         out idx1 = t+256 -> vp idx t+64 (valid for t<224)
    const int c_pair = t & 127, hgrp = t >> 7;
    float accp[6] = {0,0,0,0,0,0};
    float acc0 = 0.f, acc1 = 0.f;
    const int hh0   = (t < 192) ? (t >> 4) : (t - 192) / 24;
    const int hh1   = (t < 224) ? (t + 64) / 24 : 0;
    const int o_off = 192 + (t >> 4)*32 + 16 + (t & 15);  // v column in proj row
    const size_t zbase = (size_t)i * N_RES * 128;

    for (int j0 = 0; j0 < N_RES; j0 += 4) {
        const float z0 = z[zbase + (size_t)(j0+0)*128 + c_pair];
        const float z1 = z[zbase + (size_t)(j0+1)*128 + c_pair];
        const float z2 = z[zbase + (size_t)(j0+2)*128 + c_pair];
        const float z3 = z[zbase + (size_t)(j0+3)*128 + c_pair];
        #pragma unroll
        for (int u = 0; u < 6; ++u) {
            const float4 a4 = *(const float4*)&l_lds[(hgrp*6+u)*LSTR + j0];
            accp[u] = fmaf(a4.x, z0, accp[u]);
            accp[u] = fmaf(a4.y, z1, accp[u]);
            accp[u] = fmaf(a4.z, z2, accp[u]);
            accp[u] = fmaf(a4.w, z3, accp[u]);
        }
        {
            const float4 a4 = *(const float4*)&l_lds[hh0*LSTR + j0];
            float v0, v1, v2, v3;
            if (t < 192) {
                v0 = proj[(size_t)(j0+0)*NPROJ + o_off];
                v1 = proj[(size_t)(j0+1)*NPROJ + o_off];
                v2 = proj[(size_t)(j0+2)*NPROJ + o_off];
                v3 = proj[(size_t)(j0+3)*NPROJ + o_off];
            } else {
                const int vi = t - 192;
                v0 = vp_g[(size_t)(j0+0)*288 + vi];
                v1 = vp_g[(size_t)(j0+1)*288 + vi];
                v2 = vp_g[(size_t)(j0+2)*288 + vi];
                v3 = vp_g[(size_t)(j0+3)*288 + vi];
            }
            acc0 = fmaf(a4.x, v0, fmaf(a4.y, v1, fmaf(a4.z, v2, fmaf(a4.w, v3, acc0))));
        }
        if (t < 224) {
            const float4 a4 = *(const float4*)&l_lds[hh1*LSTR + j0];
            const int vi = t + 64;
            const float v0 = vp_g[(size_t)(j0+0)*288 + vi];
            const float v1 = vp_g[(size_t)(j0+1)*288 + vi];
            const float v2 = vp_g[(size_t)(j0+2)*288 + vi];
            const float v3 = vp_g[(size_t)(j0+3)*288 + vi];
            acc1 = fmaf(a4.x, v0, fmaf(a4.y, v1, fmaf(a4.z, v2, fmaf(a4.w, v3, acc1))));
        }
    }

    // ---- epilogue ----
    float* crow = cat + (size_t)i * 2112;
    #pragma unroll
    for (int u = 0; u < 6; ++u)
        crow[576 + (hgrp*6+u)*128 + c_pair] = accp[u];
    if (t < 192) crow[t] = acc0;
    else         opt_raw[t - 192] = acc0;
    if (t < 224) opt_raw[t + 64] = acc1;
    __syncthreads();
    if (t < 96) {   // t = h*8+p
        const float* R = rots  + (size_t)i * 9;
        const float* T = trans + (size_t)i * 3;
        const float r0 = opt_raw[t*3+0] - T[0];
        const float r1 = opt_raw[t*3+1] - T[1];
        const float r2 = opt_raw[t*3+2] - T[2];
        // inverse rotation: out[x] = sum_y R[y][x]*(raw[y]-T[y])
        const float o0 = R[0]*r0 + R[3]*r1 + R[6]*r2;
        const float o1 = R[1]*r0 + R[4]*r1 + R[7]*r2;
        const float o2 = R[2]*r0 + R[5]*r1 + R[8]*r2;
        crow[192 +   0 + t] = o0;
        crow[192 +  96 + t] = o1;
        crow[192 + 192 + t] = o2;
        crow[480 + t] = sqrtf(o0*o0 + o1*o1 + o2*o2 + 1e-8f);
    }
}

// ---------------------------------------------------------------------------
// Kernel 4: out = cat @ Wout + bout.  M=512, N=384, K=2112. 32x32 tiles.
// ---------------------------------------------------------------------------
__global__ __launch_bounds__(256) void k_out(
    const float* __restrict__ cat, const float* __restrict__ Wout,
    const float* __restrict__ bout, float* __restrict__ out)
{
    __shared__ float A[32][33];
    __shared__ float Bt[32][33];
    const int t  = threadIdx.x;
    const int tx = t % 16, ty = t / 16;
    const int i0 = blockIdx.x * 32, n0 = blockIdx.y * 32;
    float acc00=0.f, acc01=0.f, acc10=0.f, acc11=0.f;
    for (int k0 = 0; k0 < 2112; k0 += 32) {
        for (int idx = t; idx < 1024; idx += 256) {
            const int r = idx / 32, c2 = idx % 32;
            A[r][c2]  = cat[(size_t)(i0 + r) * 2112 + k0 + c2];
            Bt[r][c2] = Wout[(size_t)(k0 + r) * 384 + n0 + c2];
        }
        __syncthreads();
        #pragma unroll
        for (int kk = 0; kk < 32; ++kk) {
            const float a0 = A[ty][kk],      a1 = A[ty+16][kk];
            const float b0 = Bt[kk][tx],     b1 = Bt[kk][tx+16];
            acc00 = fmaf(a0, b0, acc00); acc01 = fmaf(a0, b1, acc01);
            acc10 = fmaf(a1, b0, acc10); acc11 = fmaf(a1, b1, acc11);
        }
        __syncthreads();
    }
    out[(size_t)(i0+ty   )*384 + n0+tx   ] = acc00 + bout[n0+tx   ];
    out[(size_t)(i0+ty   )*384 + n0+tx+16] = acc01 + bout[n0+tx+16];
    out[(size_t)(i0+ty+16)*384 + n0+tx   ] = acc10 + bout[n0+tx   ];
    out[(size_t)(i0+ty+16)*384 + n0+tx+16] = acc11 + bout[n0+tx+16];
}

// ---------------------------------------------------------------------------
extern "C" void kernel_launch(void* const* d_in, const int* in_sizes, int n_in,
                              void* d_out, int out_size, void* d_ws, size_t ws_size,
                              hipStream_t stream)
{
    const float* s      = (const float*)d_in[0];
    const float* z      = (const float*)d_in[1];
    const float* rots   = (const float*)d_in[2];
    const float* trans  = (const float*)d_in[3];
    const float* mask   = (const float*)d_in[4];
    const float* Wq     = (const float*)d_in[5];
    const float* bq     = (const float*)d_in[6];
    const float* Wkv    = (const float*)d_in[7];
    const float* bkv    = (const float*)d_in[8];
    const float* Wqp    = (const float*)d_in[9];
    const float* bqp    = (const float*)d_in[10];
    const float* Wkvp   = (const float*)d_in[11];
    const float* bkvp   = (const float*)d_in[12];
    const float* Wb     = (const float*)d_in[13];
    const float* bb     = (const float*)d_in[14];
    const float* head_w = (const float*)d_in[15];
    const float* Wout   = (const float*)d_in[16];
    const float* bout   = (const float*)d_in[17];
    float* out = (float*)d_out;

    float* ws   = (float*)d_ws;
    float* proj = ws;                       // 512*1152 = 589824
    float* qp_g = proj + 589824;            // 512*144  = 73728
    float* kp_g = qp_g + 73728;             // 73728
    float* vp_g = kp_g + 73728;             // 512*288  = 147456
    float* cat  = vp_g + 147456;            // 512*2112 = 1081344

    k_proj<<<dim3(32, 24), 768, 0, stream>>>(s, Wq, bq, Wkv, bkv, Wqp, bqp, Wkvp, bkvp, proj);
    k_rot <<<512, 192, 0, stream>>>(proj, rots, trans, qp_g, kp_g, vp_g);
    k_attn<<<512, 256, 0, stream>>>(proj, z, rots, trans, mask, Wb, bb, head_w,
                                    qp_g, kp_g, vp_g, cat);
    k_out <<<dim3(16, 12), 256, 0, stream>>>(cat, Wout, bout, out);
}

// Round 2
// 318.101 us; speedup vs baseline: 1.0308x; 1.0308x over previous
//
#include <hip/hip_runtime.h>
#include <math.h>

#define N_RES 512
#define NPROJ 1152
#define LSTR  520   // 512 + 8 pad: breaks stride-512 LDS bank aliasing

// ---------------------------------------------------------------------------
// Kernel 1: all input projections as one tiled GEMM.
// proj row layout (per residue): [0,192)=q (h*16+c), [192,576)=kv (h*32 + {c|16+c}),
// [576,720)=qp raw (y*48+p), [720,1152)=kvp raw (y*144+p)
// ---------------------------------------------------------------------------
__global__ __launch_bounds__(768) void k_proj(
    const float* __restrict__ s,
    const float* __restrict__ Wq,  const float* __restrict__ bq,
    const float* __restrict__ Wkv, const float* __restrict__ bkv,
    const float* __restrict__ Wqp, const float* __restrict__ bqp,
    const float* __restrict__ Wkvp,const float* __restrict__ bkvp,
    float* __restrict__ proj)
{
    const int it = blockIdx.x;   // 0..31
    const int ch = blockIdx.y;   // 0..23
    const int t  = threadIdx.x;
    const int r  = t / 48;       // 0..15
    const int c  = t % 48;
    __shared__ float s_lds[16 * 384];
    __shared__ float w_lds[32 * 48];

    for (int idx = t; idx < 16 * 384; idx += 768) {
        int rr = idx / 384, kk = idx % 384;
        s_lds[idx] = s[(size_t)(it * 16 + rr) * 384 + kk];
    }

    const int col = ch * 48;
    const float* W; const float* bv; int wN, wc;
    if (col < 192)      { W = Wq;   bv = bq;   wN = 192; wc = col; }
    else if (col < 576) { W = Wkv;  bv = bkv;  wN = 384; wc = col - 192; }
    else if (col < 720) { W = Wqp;  bv = bqp;  wN = 144; wc = col - 576; }
    else                { W = Wkvp; bv = bkvp; wN = 432; wc = col - 720; }

    float acc = 0.f;
    for (int k0 = 0; k0 < 384; k0 += 32) {
        __syncthreads();
        for (int idx = t; idx < 32 * 48; idx += 768) {
            int kk = idx / 48, cc = idx % 48;
            w_lds[idx] = W[(size_t)(k0 + kk) * wN + wc + cc];
        }
        __syncthreads();
        #pragma unroll
        for (int kk = 0; kk < 32; ++kk)
            acc = fmaf(s_lds[r * 384 + k0 + kk], w_lds[kk * 48 + c], acc);
    }
    proj[(size_t)(it * 16 + r) * NPROJ + col + c] = acc + bv[wc + c];
}

// ---------------------------------------------------------------------------
// Kernel 2: rotate/translate qp & kvp into global frame.
// ---------------------------------------------------------------------------
__global__ __launch_bounds__(192) void k_rot(
    const float* __restrict__ proj, const float* __restrict__ rots,
    const float* __restrict__ trans,
    float* __restrict__ qp_g, float* __restrict__ kp_g, float* __restrict__ vp_g)
{
    const int i = blockIdx.x;
    const int t = threadIdx.x;
    const float* R = rots  + (size_t)i * 9;
    const float* T = trans + (size_t)i * 3;
    const float* row = proj + (size_t)i * NPROJ;
    const float r00=R[0],r01=R[1],r02=R[2],r10=R[3],r11=R[4],r12=R[5],r20=R[6],r21=R[7],r22=R[8];
    const float t0=T[0], t1=T[1], t2=T[2];
    if (t < 48) {
        const int p = t;
        const float v0 = row[576 + p], v1 = row[576 + 48 + p], v2 = row[576 + 96 + p];
        float* dst = qp_g + (size_t)i*144 + p*3;
        dst[0] = r00*v0 + r01*v1 + r02*v2 + t0;
        dst[1] = r10*v0 + r11*v1 + r12*v2 + t1;
        dst[2] = r20*v0 + r21*v1 + r22*v2 + t2;
    } else {
        const int p = t - 48;
        const float v0 = row[720 + p], v1 = row[720 + 144 + p], v2 = row[720 + 288 + p];
        const float o0 = r00*v0 + r01*v1 + r02*v2 + t0;
        const float o1 = r10*v0 + r11*v1 + r12*v2 + t1;
        const float o2 = r20*v0 + r21*v1 + r22*v2 + t2;
        const int h = p / 12, pp = p % 12;
        if (pp < 4) {
            float* dst = kp_g + (size_t)i*144 + (h*4+pp)*3;
            dst[0]=o0; dst[1]=o1; dst[2]=o2;
        } else {
            float* dst = vp_g + (size_t)i*288 + (h*8+(pp-4))*3;
            dst[0]=o0; dst[1]=o1; dst[2]=o2;
        }
    }
}

// ---------------------------------------------------------------------------
// Kernel 3: bias = SC_B*(z@Wb + bb) + 1e5*(mask_i*mask_j - 1).
// One thread per (i,j) row. 1024 blocks x 256 thr. Streams z (128 MB) from HBM.
// ---------------------------------------------------------------------------
__global__ __launch_bounds__(256) void k_bias(
    const float* __restrict__ z, const float* __restrict__ Wb,
    const float* __restrict__ bb, const float* __restrict__ mask,
    float* __restrict__ bias)
{
    const int row = blockIdx.x * 256 + threadIdx.x;   // = i*512 + j
    const int i = row >> 9, j = row & 511;
    float acc[12];
    #pragma unroll
    for (int h = 0; h < 12; ++h) acc[h] = bb[h];
    const float* zr = z + (size_t)row * 128;
    for (int c = 0; c < 128; c += 4) {
        const float4 zv = *(const float4*)(zr + c);
        #pragma unroll
        for (int h = 0; h < 12; ++h) {   // Wb reads wave-uniform -> scalar loads
            acc[h] = fmaf(zv.x, Wb[(c+0)*12 + h], acc[h]);
            acc[h] = fmaf(zv.y, Wb[(c+1)*12 + h], acc[h]);
            acc[h] = fmaf(zv.z, Wb[(c+2)*12 + h], acc[h]);
            acc[h] = fmaf(zv.w, Wb[(c+3)*12 + h], acc[h]);
        }
    }
    const float mterm = 100000.0f * (mask[i] * mask[j] - 1.0f);
    float* br = bias + (size_t)row * 12;
    #pragma unroll
    for (int h = 0; h < 12; ++h)
        br[h] = fmaf(0.57735026918962576f, acc[h], mterm);
}

// ---------------------------------------------------------------------------
// Kernel 4: per-i logits (bias precomputed) + softmax + store a + o/o_pt + epi.
// a is written OVER the bias buffer (same per-i 6144-float slab; all reads
// complete before the post-softmax barrier). a layout: [i][h][j].
// cat layout: [0,192)=o, [192+96x)=o_pt x-comp, [480,576)=norm, [576,2112)=o_pair
// ---------------------------------------------------------------------------
__global__ __launch_bounds__(256) void k_soft(
    const float* __restrict__ proj, const float* __restrict__ bias,
    const float* __restrict__ rots, const float* __restrict__ trans,
    const float* __restrict__ head_w,
    const float* __restrict__ qp_g, const float* __restrict__ kp_g,
    const float* __restrict__ vp_g,
    float* __restrict__ a_out, float* __restrict__ cat)
{
    const int i = blockIdx.x;
    const int t = threadIdx.x;
    __shared__ float l_lds[12 * LSTR];
    __shared__ float opt_raw[288];

    const float SC_QK = 0.14433756729740643f;  // sqrt(1/48)
    const float SC_HW = 0.13608276348795434f;  // sqrt(1/54)

    const float* qr  = proj + (size_t)i * NPROJ;
    const float* qpr = qp_g + (size_t)i * 144;

    float hw[12];
    #pragma unroll
    for (int h = 0; h < 12; ++h)
        hw[h] = log1pf(expf(head_w[h])) * SC_HW;

    // ---- phase 1: logits ----
    for (int j = t; j < N_RES; j += 256) {
        const float* br = bias + (size_t)(i * N_RES + j) * 12;
        const float4 b0 = *(const float4*)(br + 0);
        const float4 b1 = *(const float4*)(br + 4);
        const float4 b2 = *(const float4*)(br + 8);
        const float bs[12] = {b0.x,b0.y,b0.z,b0.w, b1.x,b1.y,b1.z,b1.w, b2.x,b2.y,b2.z,b2.w};
        const float* kr  = proj + (size_t)j * NPROJ + 192;
        const float* kpr = kp_g + (size_t)j * 144;
        #pragma unroll
        for (int h = 0; h < 12; ++h) {
            float qk = 0.f;
            #pragma unroll
            for (int c = 0; c < 16; c += 4) {
                const float4 k4 = *(const float4*)(kr + h*32 + c);
                qk = fmaf(qr[h*16+c+0], k4.x, qk);
                qk = fmaf(qr[h*16+c+1], k4.y, qk);
                qk = fmaf(qr[h*16+c+2], k4.z, qk);
                qk = fmaf(qr[h*16+c+3], k4.w, qk);
            }
            float s2 = 0.f;
            #pragma unroll
            for (int p = 0; p < 4; ++p) {
                const float dx = qpr[(h*4+p)*3+0] - kpr[(h*4+p)*3+0];
                const float dy = qpr[(h*4+p)*3+1] - kpr[(h*4+p)*3+1];
                const float dz = qpr[(h*4+p)*3+2] - kpr[(h*4+p)*3+2];
                s2 += dx*dx + dy*dy + dz*dz;
            }
            l_lds[h*LSTR + j] = fmaf(qk, SC_QK, fmaf(-0.5f*hw[h], s2, bs[h]));
        }
    }
    __syncthreads();

    // ---- phase 2: softmax (wave w handles heads 3w..3w+2) ----
    {
        const int wv = t >> 6, lane = t & 63;
        for (int h = wv*3; h < wv*3+3; ++h) {
            float e[8];
            float m = -3.4e38f;
            #pragma unroll
            for (int u = 0; u < 8; ++u) { e[u] = l_lds[h*LSTR + lane + u*64]; m = fmaxf(m, e[u]); }
            #pragma unroll
            for (int d = 1; d < 64; d <<= 1) m = fmaxf(m, __shfl_xor(m, d, 64));
            float ssum = 0.f;
            #pragma unroll
            for (int u = 0; u < 8; ++u) { e[u] = expf(e[u] - m); ssum += e[u]; }
            #pragma unroll
            for (int d = 1; d < 64; d <<= 1) ssum += __shfl_xor(ssum, d, 64);
            const float inv = 1.f / ssum;
            #pragma unroll
            for (int u = 0; u < 8; ++u) l_lds[h*LSTR + lane + u*64] = e[u] * inv;
        }
    }
    __syncthreads();

    // ---- store a[i][h][j] (overwrites bias slab for this i; reads all done) ----
    for (int idx = t; idx < 1536; idx += 256) {      // 12*512/4 float4s
        const int h = idx >> 7, j4 = (idx & 127) * 4;
        *(float4*)(a_out + (size_t)i*6144 + h*512 + j4) = *(const float4*)&l_lds[h*LSTR + j4];
    }

    // ---- phase 3: o / o_pt weighted sums ----
    float acc0 = 0.f, acc1 = 0.f;
    const int hh0   = (t < 192) ? (t >> 4) : (t - 192) / 24;
    const int hh1   = (t < 224) ? (t + 64) / 24 : 0;
    const int o_off = 192 + (t >> 4)*32 + 16 + (t & 15);

    for (int j0 = 0; j0 < N_RES; j0 += 4) {
        {
            const float4 a4 = *(const float4*)&l_lds[hh0*LSTR + j0];
            float v0, v1, v2, v3;
            if (t < 192) {
                v0 = proj[(size_t)(j0+0)*NPROJ + o_off];
                v1 = proj[(size_t)(j0+1)*NPROJ + o_off];
                v2 = proj[(size_t)(j0+2)*NPROJ + o_off];
                v3 = proj[(size_t)(j0+3)*NPROJ + o_off];
            } else {
                const int vi = t - 192;
                v0 = vp_g[(size_t)(j0+0)*288 + vi];
                v1 = vp_g[(size_t)(j0+1)*288 + vi];
                v2 = vp_g[(size_t)(j0+2)*288 + vi];
                v3 = vp_g[(size_t)(j0+3)*288 + vi];
            }
            acc0 = fmaf(a4.x, v0, fmaf(a4.y, v1, fmaf(a4.z, v2, fmaf(a4.w, v3, acc0))));
        }
        if (t < 224) {
            const float4 a4 = *(const float4*)&l_lds[hh1*LSTR + j0];
            const int vi = t + 64;
            const float v0 = vp_g[(size_t)(j0+0)*288 + vi];
            const float v1 = vp_g[(size_t)(j0+1)*288 + vi];
            const float v2 = vp_g[(size_t)(j0+2)*288 + vi];
            const float v3 = vp_g[(size_t)(j0+3)*288 + vi];
            acc1 = fmaf(a4.x, v0, fmaf(a4.y, v1, fmaf(a4.z, v2, fmaf(a4.w, v3, acc1))));
        }
    }

    // ---- epilogue ----
    float* crow = cat + (size_t)i * 2112;
    if (t < 192) crow[t] = acc0;
    else         opt_raw[t - 192] = acc0;
    if (t < 224) opt_raw[t + 64] = acc1;
    __syncthreads();
    if (t < 96) {   // t = h*8+p
        const float* R = rots  + (size_t)i * 9;
        const float* T = trans + (size_t)i * 3;
        const float r0 = opt_raw[t*3+0] - T[0];
        const float r1 = opt_raw[t*3+1] - T[1];
        const float r2 = opt_raw[t*3+2] - T[2];
        const float o0 = R[0]*r0 + R[3]*r1 + R[6]*r2;
        const float o1 = R[1]*r0 + R[4]*r1 + R[7]*r2;
        const float o2 = R[2]*r0 + R[5]*r1 + R[8]*r2;
        crow[192 +   0 + t] = o0;
        crow[192 +  96 + t] = o1;
        crow[192 + 192 + t] = o2;
        crow[480 + t] = sqrtf(o0*o0 + o1*o1 + o2*o2 + 1e-8f);
    }
}

// ---------------------------------------------------------------------------
// Kernel 5: o_pair[i][h][c] = sum_j a[i][h][j] * z[i][j][c].
// Grid (512 i, 2 c-halves) x 256 thr: c = ch*64 + t%64, 3 heads per thread.
// a reads are wave-uniform (single cache line); z second pass is L3-hot.
// ---------------------------------------------------------------------------
__global__ __launch_bounds__(256) void k_opair(
    const float* __restrict__ a, const float* __restrict__ z,
    float* __restrict__ cat)
{
    const int i  = blockIdx.x, ch = blockIdx.y;
    const int t  = threadIdx.x;
    const int c  = ch*64 + (t & 63);
    const int hgr = t >> 6;                   // heads hgr*3 .. hgr*3+2
    const float* ar0 = a + (size_t)i*6144 + (size_t)(hgr*3+0)*512;
    const float* ar1 = ar0 + 512;
    const float* ar2 = ar1 + 512;
    const float* zb  = z + (size_t)i*65536 + c;
    float acc0 = 0.f, acc1 = 0.f, acc2 = 0.f;
    for (int j0 = 0; j0 < N_RES; j0 += 4) {
        const float4 a0 = *(const float4*)(ar0 + j0);
        const float4 a1 = *(const float4*)(ar1 + j0);
        const float4 a2 = *(const float4*)(ar2 + j0);
        const float z0 = zb[(size_t)(j0+0)*128];
        const float z1 = zb[(size_t)(j0+1)*128];
        const float z2 = zb[(size_t)(j0+2)*128];
        const float z3 = zb[(size_t)(j0+3)*128];
        acc0 = fmaf(a0.x,z0, fmaf(a0.y,z1, fmaf(a0.z,z2, fmaf(a0.w,z3, acc0))));
        acc1 = fmaf(a1.x,z0, fmaf(a1.y,z1, fmaf(a1.z,z2, fmaf(a1.w,z3, acc1))));
        acc2 = fmaf(a2.x,z0, fmaf(a2.y,z1, fmaf(a2.z,z2, fmaf(a2.w,z3, acc2))));
    }
    float* crow = cat + (size_t)i * 2112 + 576;
    crow[(hgr*3+0)*128 + c] = acc0;
    crow[(hgr*3+1)*128 + c] = acc1;
    crow[(hgr*3+2)*128 + c] = acc2;
}

// ---------------------------------------------------------------------------
// Kernel 6: split-K partial GEMM for out = cat @ Wout. K=2112 = 3 x 704.
// Grid (16 i-tiles, 12 n-tiles, 3 k-splits). Partials -> outp.
// ---------------------------------------------------------------------------
__global__ __launch_bounds__(256) void k_outp(
    const float* __restrict__ cat, const float* __restrict__ Wout,
    float* __restrict__ outp)
{
    __shared__ float A[32][33];
    __shared__ float Bt[32][33];
    const int t  = threadIdx.x;
    const int tx = t % 16, ty = t / 16;
    const int i0 = blockIdx.x * 32, n0 = blockIdx.y * 32;
    const int kq = blockIdx.z;
    const int kbase = kq * 704;
    float acc00=0.f, acc01=0.f, acc10=0.f, acc11=0.f;
    for (int k0 = kbase; k0 < kbase + 704; k0 += 32) {
        for (int idx = t; idx < 1024; idx += 256) {
            const int r = idx / 32, c2 = idx % 32;
            A[r][c2]  = cat[(size_t)(i0 + r) * 2112 + k0 + c2];
            Bt[r][c2] = Wout[(size_t)(k0 + r) * 384 + n0 + c2];
        }
        __syncthreads();
        #pragma unroll
        for (int kk = 0; kk < 32; ++kk) {
            const float a0 = A[ty][kk],  a1 = A[ty+16][kk];
            const float b0 = Bt[kk][tx], b1 = Bt[kk][tx+16];
            acc00 = fmaf(a0, b0, acc00); acc01 = fmaf(a0, b1, acc01);
            acc10 = fmaf(a1, b0, acc10); acc11 = fmaf(a1, b1, acc11);
        }
        __syncthreads();
    }
    float* op = outp + (size_t)kq * 196608;
    op[(size_t)(i0+ty   )*384 + n0+tx   ] = acc00;
    op[(size_t)(i0+ty   )*384 + n0+tx+16] = acc01;
    op[(size_t)(i0+ty+16)*384 + n0+tx   ] = acc10;
    op[(size_t)(i0+ty+16)*384 + n0+tx+16] = acc11;
}

__global__ __launch_bounds__(256) void k_red(
    const float* __restrict__ outp, const float* __restrict__ bout,
    float* __restrict__ out)
{
    const int e = blockIdx.x * 256 + threadIdx.x;   // < 196608
    out[e] = outp[e] + outp[196608 + e] + outp[393216 + e] + bout[e % 384];
}

// ---------------------------------------------------------------------------
extern "C" void kernel_launch(void* const* d_in, const int* in_sizes, int n_in,
                              void* d_out, int out_size, void* d_ws, size_t ws_size,
                              hipStream_t stream)
{
    const float* s      = (const float*)d_in[0];
    const float* z      = (const float*)d_in[1];
    const float* rots   = (const float*)d_in[2];
    const float* trans  = (const float*)d_in[3];
    const float* mask   = (const float*)d_in[4];
    const float* Wq     = (const float*)d_in[5];
    const float* bq     = (const float*)d_in[6];
    const float* Wkv    = (const float*)d_in[7];
    const float* bkv    = (const float*)d_in[8];
    const float* Wqp    = (const float*)d_in[9];
    const float* bqp    = (const float*)d_in[10];
    const float* Wkvp   = (const float*)d_in[11];
    const float* bkvp   = (const float*)d_in[12];
    const float* Wb     = (const float*)d_in[13];
    const float* bb     = (const float*)d_in[14];
    const float* head_w = (const float*)d_in[15];
    const float* Wout   = (const float*)d_in[16];
    const float* bout   = (const float*)d_in[17];
    float* out = (float*)d_out;

    float* ws    = (float*)d_ws;
    float* proj  = ws;                      // 589824
    float* qp_g  = proj  + 589824;          // 73728
    float* kp_g  = qp_g  + 73728;           // 73728
    float* vp_g  = kp_g  + 73728;           // 147456
    float* biasa = vp_g  + 147456;          // 3145728 (bias, then aliased as a)
    float* cat   = biasa + 3145728;         // 1081344
    float* outp  = cat   + 1081344;         // 589824

    k_proj <<<dim3(32, 24), 768, 0, stream>>>(s, Wq, bq, Wkv, bkv, Wqp, bqp, Wkvp, bkvp, proj);
    k_rot  <<<512, 192, 0, stream>>>(proj, rots, trans, qp_g, kp_g, vp_g);
    k_bias <<<1024, 256, 0, stream>>>(z, Wb, bb, mask, biasa);
    k_soft <<<512, 256, 0, stream>>>(proj, biasa, rots, trans, head_w,
                                     qp_g, kp_g, vp_g, biasa, cat);
    k_opair<<<dim3(512, 2), 256, 0, stream>>>(biasa, z, cat);
    k_outp <<<dim3(16, 12, 3), 256, 0, stream>>>(cat, Wout, outp);
    k_red  <<<768, 256, 0, stream>>>(outp, bout, out);
}

// Round 4
// 195.920 us; speedup vs baseline: 1.6737x; 1.6236x over previous
//
#include <hip/hip_runtime.h>
#include <math.h>

#define N_RES 512
#define NPROJ 1152
#define LSTR  520

// ---------------------------------------------------------------------------
// k_wcat: concatenate projection weights into Wcat[384][1152] + bcat[1152].
// cols: [0,192)=Wq, [192,576)=Wkv, [576,720)=Wqp, [720,1152)=Wkvp
// ---------------------------------------------------------------------------
__global__ __launch_bounds__(256) void k_wcat(
    const float* __restrict__ Wq,  const float* __restrict__ bq,
    const float* __restrict__ Wkv, const float* __restrict__ bkv,
    const float* __restrict__ Wqp, const float* __restrict__ bqp,
    const float* __restrict__ Wkvp,const float* __restrict__ bkvp,
    float* __restrict__ wcat)   // 442368 weights + 1152 bias
{
    const int idx = blockIdx.x * 256 + threadIdx.x;
    if (idx < 442368) {
        const int k = idx / 1152, col = idx % 1152;
        float v;
        if (col < 192)      v = Wq  [(size_t)k*192 + col];
        else if (col < 576) v = Wkv [(size_t)k*384 + col-192];
        else if (col < 720) v = Wqp [(size_t)k*144 + col-576];
        else                v = Wkvp[(size_t)k*432 + col-720];
        wcat[idx] = v;
    } else if (idx < 443520) {
        const int col = idx - 442368;
        float v;
        if (col < 192)      v = bq  [col];
        else if (col < 576) v = bkv [col-192];
        else if (col < 720) v = bqp [col-576];
        else                v = bkvp[col-720];
        wcat[idx] = v;
    }
}

// ---------------------------------------------------------------------------
// k_proj: proj = s @ Wcat + bcat.  M=512,K=384,N=1152. 32x32 tiles, 64 thr,
// 4x4 register tile per thread, b128 LDS reads.
// ---------------------------------------------------------------------------
__global__ __launch_bounds__(64) void k_proj(
    const float* __restrict__ s, const float* __restrict__ wcat,
    float* __restrict__ proj)
{
    __shared__ float A[32*36];
    __shared__ float Bt[32*36];
    const int t  = threadIdx.x;
    const int ty = t >> 3, tx = t & 7;
    const int i0 = blockIdx.x * 32, c0 = blockIdx.y * 32;
    const float* bcat = wcat + 442368;

    float acc[4][4] = {};
    for (int k0 = 0; k0 < 384; k0 += 32) {
        __syncthreads();
        #pragma unroll
        for (int u = 0; u < 4; ++u) {
            const int q = t*4 + u;              // 0..255
            const int r = q >> 3, kk = (q & 7) * 4;
            *(float4*)&A[r*36 + kk] = *(const float4*)&s[(size_t)(i0+r)*384 + k0 + kk];
            const float4 wv = *(const float4*)&wcat[(size_t)(k0+r)*1152 + c0 + kk];
            Bt[(kk+0)*36 + r] = wv.x;
            Bt[(kk+1)*36 + r] = wv.y;
            Bt[(kk+2)*36 + r] = wv.z;
            Bt[(kk+3)*36 + r] = wv.w;
        }
        __syncthreads();
        #pragma unroll
        for (int k4 = 0; k4 < 32; k4 += 4) {
            float4 a4[4], b4[4];
            #pragma unroll
            for (int rr = 0; rr < 4; ++rr) a4[rr] = *(const float4*)&A [(rr*8+ty)*36 + k4];
            #pragma unroll
            for (int cc = 0; cc < 4; ++cc) b4[cc] = *(const float4*)&Bt[(cc*8+tx)*36 + k4];
            #pragma unroll
            for (int rr = 0; rr < 4; ++rr)
                #pragma unroll
                for (int cc = 0; cc < 4; ++cc)
                    acc[rr][cc] = fmaf(a4[rr].x, b4[cc].x,
                                  fmaf(a4[rr].y, b4[cc].y,
                                  fmaf(a4[rr].z, b4[cc].z,
                                  fmaf(a4[rr].w, b4[cc].w, acc[rr][cc]))));
        }
    }
    #pragma unroll
    for (int rr = 0; rr < 4; ++rr)
        #pragma unroll
        for (int cc = 0; cc < 4; ++cc) {
            const int c = c0 + cc*8 + tx;
            proj[(size_t)(i0 + rr*8 + ty)*NPROJ + c] = acc[rr][cc] + bcat[c];
        }
}

// ---------------------------------------------------------------------------
// k_rot: rotate/translate qp & kvp into global frame.
// ---------------------------------------------------------------------------
__global__ __launch_bounds__(192) void k_rot(
    const float* __restrict__ proj, const float* __restrict__ rots,
    const float* __restrict__ trans,
    float* __restrict__ qp_g, float* __restrict__ kp_g, float* __restrict__ vp_g)
{
    const int i = blockIdx.x;
    const int t = threadIdx.x;
    const float* R = rots  + (size_t)i * 9;
    const float* T = trans + (size_t)i * 3;
    const float* row = proj + (size_t)i * NPROJ;
    const float r00=R[0],r01=R[1],r02=R[2],r10=R[3],r11=R[4],r12=R[5],r20=R[6],r21=R[7],r22=R[8];
    const float t0=T[0], t1=T[1], t2=T[2];
    if (t < 48) {
        const int p = t;
        const float v0 = row[576 + p], v1 = row[576 + 48 + p], v2 = row[576 + 96 + p];
        float* dst = qp_g + (size_t)i*144 + p*3;
        dst[0] = r00*v0 + r01*v1 + r02*v2 + t0;
        dst[1] = r10*v0 + r11*v1 + r12*v2 + t1;
        dst[2] = r20*v0 + r21*v1 + r22*v2 + t2;
    } else {
        const int p = t - 48;
        const float v0 = row[720 + p], v1 = row[720 + 144 + p], v2 = row[720 + 288 + p];
        const float o0 = r00*v0 + r01*v1 + r02*v2 + t0;
        const float o1 = r10*v0 + r11*v1 + r12*v2 + t1;
        const float o2 = r20*v0 + r21*v1 + r22*v2 + t2;
        const int h = p / 12, pp = p % 12;
        if (pp < 4) {
            float* dst = kp_g + (size_t)i*144 + (h*4+pp)*3;
            dst[0]=o0; dst[1]=o1; dst[2]=o2;
        } else {
            float* dst = vp_g + (size_t)i*288 + (h*8+(pp-4))*3;
            dst[0]=o0; dst[1]=o1; dst[2]=o2;
        }
    }
}

// ---------------------------------------------------------------------------
// k_logit: fused z@Wb bias + qk + point-dist + mask -> pre-softmax logits.
// grid (512 i, 4 jq) x 256 thr: jj=t&127, head-half = t>>7 (6 heads each).
// Carries the 128 MB z read at 8 waves/SIMD.
// ---------------------------------------------------------------------------
__global__ __launch_bounds__(256) void k_logit(
    const float* __restrict__ proj, const float* __restrict__ z,
    const float* __restrict__ mask,
    const float* __restrict__ Wb,  const float* __restrict__ bb,
    const float* __restrict__ head_w,
    const float* __restrict__ qp_g, const float* __restrict__ kp_g,
    float* __restrict__ a)
{
    const int i  = blockIdx.x, jq = blockIdx.y;
    const int t  = threadIdx.x;
    const int jj = t & 127, j = jq*128 + jj;
    const int hb = __builtin_amdgcn_readfirstlane((t >> 7) * 6);  // wave-uniform

    __shared__ float qlds[336];   // [0,192)=q, [192,336)=qp
    for (int idx = t; idx < 336; idx += 256)   // FIX: strided, covers all 336
        qlds[idx] = (idx < 192) ? proj[(size_t)i*NPROJ + idx]
                                : qp_g[(size_t)i*144 + (idx-192)];
    __syncthreads();

    const float SC_QK = 0.14433756729740643f;  // sqrt(1/48)
    const float SC_B  = 0.57735026918962576f;  // sqrt(1/3)
    const float SC_HW = 0.13608276348795434f;  // sqrt(1/54)

    float acc[6], hw[6];
    #pragma unroll
    for (int u = 0; u < 6; ++u) {
        acc[u] = bb[hb+u];
        hw[u]  = log1pf(expf(head_w[hb+u])) * SC_HW;
    }

    // bias = z-row @ Wb  (Wb via s_loads: hb is SGPR)
    const float* zr = z + ((size_t)i * N_RES + j) * 128;
    for (int c = 0; c < 128; c += 4) {
        const float4 zv = *(const float4*)(zr + c);
        const float* wbc = Wb + c*12 + hb;
        #pragma unroll
        for (int u = 0; u < 6; ++u)
            acc[u] = fmaf(zv.x, wbc[u],
                     fmaf(zv.y, wbc[12+u],
                     fmaf(zv.z, wbc[24+u],
                     fmaf(zv.w, wbc[36+u], acc[u]))));
    }

    const float* kr  = proj + (size_t)j * NPROJ + 192;
    const float* kpr = kp_g + (size_t)j * 144;
    const float mterm = 100000.0f * (mask[i] * mask[j] - 1.0f);
    #pragma unroll
    for (int u = 0; u < 6; ++u) {
        const int h = hb + u;
        float qk = 0.f;
        #pragma unroll
        for (int c = 0; c < 16; c += 4) {
            const float4 k4 = *(const float4*)(kr + h*32 + c);
            qk = fmaf(qlds[h*16+c+0], k4.x,
                 fmaf(qlds[h*16+c+1], k4.y,
                 fmaf(qlds[h*16+c+2], k4.z,
                 fmaf(qlds[h*16+c+3], k4.w, qk))));
        }
        float s2 = 0.f;
        #pragma unroll
        for (int e = 0; e < 12; e += 4) {
            const float4 kp4 = *(const float4*)(kpr + h*12 + e);
            const float d0 = qlds[192 + h*12 + e+0] - kp4.x;
            const float d1 = qlds[192 + h*12 + e+1] - kp4.y;
            const float d2 = qlds[192 + h*12 + e+2] - kp4.z;
            const float d3 = qlds[192 + h*12 + e+3] - kp4.w;
            s2 += d0*d0 + d1*d1 + d2*d2 + d3*d3;
        }
        a[(size_t)i*6144 + h*512 + j] =
            fmaf(qk, SC_QK, fmaf(acc[u], SC_B, fmaf(-0.5f*hw[u], s2, mterm)));
    }
}

// ---------------------------------------------------------------------------
// k_softmax: one wave per (i,h) row of 512, in place.  6144 rows.
// ---------------------------------------------------------------------------
__global__ __launch_bounds__(256) void k_softmax(float* __restrict__ a)
{
    const int row  = blockIdx.x * 4 + (threadIdx.x >> 6);
    const int lane = threadIdx.x & 63;
    float* ar = a + (size_t)row * 512 + lane * 8;
    float4 v0 = *(const float4*)ar;
    float4 v1 = *(const float4*)(ar + 4);
    float m = fmaxf(fmaxf(fmaxf(v0.x,v0.y), fmaxf(v0.z,v0.w)),
                    fmaxf(fmaxf(v1.x,v1.y), fmaxf(v1.z,v1.w)));
    #pragma unroll
    for (int d = 1; d < 64; d <<= 1) m = fmaxf(m, __shfl_xor(m, d, 64));
    v0.x = expf(v0.x-m); v0.y = expf(v0.y-m); v0.z = expf(v0.z-m); v0.w = expf(v0.w-m);
    v1.x = expf(v1.x-m); v1.y = expf(v1.y-m); v1.z = expf(v1.z-m); v1.w = expf(v1.w-m);
    float ssum = v0.x+v0.y+v0.z+v0.w + v1.x+v1.y+v1.z+v1.w;
    #pragma unroll
    for (int d = 1; d < 64; d <<= 1) ssum += __shfl_xor(ssum, d, 64);
    const float inv = 1.f / ssum;
    v0.x*=inv; v0.y*=inv; v0.z*=inv; v0.w*=inv;
    v1.x*=inv; v1.y*=inv; v1.z*=inv; v1.w*=inv;
    *(float4*)ar = v0;
    *(float4*)(ar + 4) = v1;
}

// ---------------------------------------------------------------------------
// k_av: o and o_pt for TWO residues per block (shares V reads).
// 256 blocks x 512 thr. a staged in LDS (stride 520). Epilogue: inverse
// rigid transform + norms.
// ---------------------------------------------------------------------------
__global__ __launch_bounds__(512) void k_av(
    const float* __restrict__ a, const float* __restrict__ proj,
    const float* __restrict__ vp_g,
    const float* __restrict__ rots, const float* __restrict__ trans,
    float* __restrict__ cat)
{
    const int i0 = blockIdx.x * 2;
    const int t  = threadIdx.x;
    __shared__ float al[2*12*LSTR];
    __shared__ float opt_raw[2][288];

    #pragma unroll
    for (int p = 0; p < 6; ++p) {
        const int q4 = p*512 + t;            // < 3072 float4s
        const int el = q4 * 4;
        const int ii = el / 6144, rem = el % 6144;
        const int h = rem >> 9, jj = rem & 511;
        *(float4*)&al[(ii*12+h)*LSTR + jj] = *(const float4*)&a[(size_t)(i0+ii)*6144 + rem];
    }
    __syncthreads();

    float acc0 = 0.f, acc1 = 0.f;
    if (t < 480) {
        const int hh    = (t < 192) ? (t >> 4) : (t - 192) / 24;
        const int o_off = 192 + (t >> 4)*32 + 16 + (t & 15);
        const int vi    = t - 192;
        const float* al0 = al + hh*LSTR;
        const float* al1 = al + (12+hh)*LSTR;
        for (int j0 = 0; j0 < N_RES; j0 += 8) {
            const float4 a00 = *(const float4*)&al0[j0];
            const float4 a01 = *(const float4*)&al0[j0+4];
            const float4 a10 = *(const float4*)&al1[j0];
            const float4 a11 = *(const float4*)&al1[j0+4];
            float v[8];
            if (t < 192) {
                #pragma unroll
                for (int w = 0; w < 8; ++w) v[w] = proj[(size_t)(j0+w)*NPROJ + o_off];
            } else {
                #pragma unroll
                for (int w = 0; w < 8; ++w) v[w] = vp_g[(size_t)(j0+w)*288 + vi];
            }
            acc0 = fmaf(a00.x,v[0], fmaf(a00.y,v[1], fmaf(a00.z,v[2], fmaf(a00.w,v[3], acc0))));
            acc0 = fmaf(a01.x,v[4], fmaf(a01.y,v[5], fmaf(a01.z,v[6], fmaf(a01.w,v[7], acc0))));
            acc1 = fmaf(a10.x,v[0], fmaf(a10.y,v[1], fmaf(a10.z,v[2], fmaf(a10.w,v[3], acc1))));
            acc1 = fmaf(a11.x,v[4], fmaf(a11.y,v[5], fmaf(a11.z,v[6], fmaf(a11.w,v[7], acc1))));
        }
        if (t < 192) {
            cat[(size_t)i0*2112 + t]     = acc0;
            cat[(size_t)(i0+1)*2112 + t] = acc1;
        } else {
            opt_raw[0][vi] = acc0;
            opt_raw[1][vi] = acc1;
        }
    }
    __syncthreads();
    if (t < 192) {   // t<96: residue i0, else i0+1;  u = h*8+p
        const int sel = (t < 96) ? 0 : 1;
        const int u   = (t < 96) ? t : t - 96;
        const int i   = i0 + sel;
        const float* R = rots  + (size_t)i * 9;
        const float* T = trans + (size_t)i * 3;
        const float r0 = opt_raw[sel][u*3+0] - T[0];
        const float r1 = opt_raw[sel][u*3+1] - T[1];
        const float r2 = opt_raw[sel][u*3+2] - T[2];
        const float o0 = R[0]*r0 + R[3]*r1 + R[6]*r2;
        const float o1 = R[1]*r0 + R[4]*r1 + R[7]*r2;
        const float o2 = R[2]*r0 + R[5]*r1 + R[8]*r2;
        float* crow = cat + (size_t)i * 2112;
        crow[192 +   0 + u] = o0;
        crow[192 +  96 + u] = o1;
        crow[192 + 192 + u] = o2;
        crow[480 + u] = sqrtf(o0*o0 + o1*o1 + o2*o2 + 1e-8f);
    }
}

// ---------------------------------------------------------------------------
// k_opair: o_pair[i][h][c] = sum_j a[i][h][j] * z[i][j][c].
// 512 blocks x 512 thr (8 waves): c=t&127, 3 heads per 128-thread group.
// ---------------------------------------------------------------------------
__global__ __launch_bounds__(512) void k_opair(
    const float* __restrict__ a, const float* __restrict__ z,
    float* __restrict__ cat)
{
    const int i = blockIdx.x;
    const int t = threadIdx.x;
    __shared__ float al[12*LSTR];
    #pragma unroll
    for (int p = 0; p < 3; ++p) {
        const int q4 = p*512 + t;            // < 1536 float4s
        const int el = q4 * 4;
        const int h = el >> 9, jj = el & 511;
        *(float4*)&al[h*LSTR + jj] = *(const float4*)&a[(size_t)i*6144 + el];
    }
    __syncthreads();

    const int c  = t & 127;
    const int h0 = (t >> 7) * 3;
    const float* al0 = al + (h0+0)*LSTR;
    const float* al1 = al + (h0+1)*LSTR;
    const float* al2 = al + (h0+2)*LSTR;
    const float* zb  = z + (size_t)i*65536 + c;
    float acc0 = 0.f, acc1 = 0.f, acc2 = 0.f;
    for (int j0 = 0; j0 < N_RES; j0 += 4) {
        const float4 a0 = *(const float4*)&al0[j0];
        const float4 a1 = *(const float4*)&al1[j0];
        const float4 a2 = *(const float4*)&al2[j0];
        const float z0 = zb[(size_t)(j0+0)*128];
        const float z1 = zb[(size_t)(j0+1)*128];
        const float z2 = zb[(size_t)(j0+2)*128];
        const float z3 = zb[(size_t)(j0+3)*128];
        acc0 = fmaf(a0.x,z0, fmaf(a0.y,z1, fmaf(a0.z,z2, fmaf(a0.w,z3, acc0))));
        acc1 = fmaf(a1.x,z0, fmaf(a1.y,z1, fmaf(a1.z,z2, fmaf(a1.w,z3, acc1))));
        acc2 = fmaf(a2.x,z0, fmaf(a2.y,z1, fmaf(a2.z,z2, fmaf(a2.w,z3, acc2))));
    }
    float* crow = cat + (size_t)i * 2112 + 576;
    crow[(h0+0)*128 + c] = acc0;
    crow[(h0+1)*128 + c] = acc1;
    crow[(h0+2)*128 + c] = acc2;
}

// ---------------------------------------------------------------------------
// k_outp: split-K partials of cat @ Wout. K=2112=6x352. 32x32 tiles, 64 thr,
// 4x4 register tile, b128 LDS reads.
// ---------------------------------------------------------------------------
__global__ __launch_bounds__(64) void k_outp(
    const float* __restrict__ cat, const float* __restrict__ Wout,
    float* __restrict__ outp)
{
    __shared__ float A[32*36];
    __shared__ float Bt[32*36];
    const int t  = threadIdx.x;
    const int ty = t >> 3, tx = t & 7;
    const int i0 = blockIdx.x * 32, n0 = blockIdx.y * 32;
    const int kq = blockIdx.z;

    float acc[4][4] = {};
    for (int kc = 0; kc < 11; ++kc) {
        const int kb = kq*352 + kc*32;
        __syncthreads();
        #pragma unroll
        for (int u = 0; u < 4; ++u) {
            const int q = t*4 + u;
            const int r = q >> 3, kk = (q & 7) * 4;
            *(float4*)&A[r*36 + kk] = *(const float4*)&cat[(size_t)(i0+r)*2112 + kb + kk];
            const float4 wv = *(const float4*)&Wout[(size_t)(kb+r)*384 + n0 + kk];
            Bt[(kk+0)*36 + r] = wv.x;
            Bt[(kk+1)*36 + r] = wv.y;
            Bt[(kk+2)*36 + r] = wv.z;
            Bt[(kk+3)*36 + r] = wv.w;
        }
        __syncthreads();
        #pragma unroll
        for (int k4 = 0; k4 < 32; k4 += 4) {
            float4 a4[4], b4[4];
            #pragma unroll
            for (int rr = 0; rr < 4; ++rr) a4[rr] = *(const float4*)&A [(rr*8+ty)*36 + k4];
            #pragma unroll
            for (int cc = 0; cc < 4; ++cc) b4[cc] = *(const float4*)&Bt[(cc*8+tx)*36 + k4];
            #pragma unroll
            for (int rr = 0; rr < 4; ++rr)
                #pragma unroll
                for (int cc = 0; cc < 4; ++cc)
                    acc[rr][cc] = fmaf(a4[rr].x, b4[cc].x,
                                  fmaf(a4[rr].y, b4[cc].y,
                                  fmaf(a4[rr].z, b4[cc].z,
                                  fmaf(a4[rr].w, b4[cc].w, acc[rr][cc]))));
        }
    }
    float* op = outp + (size_t)kq * 196608;
    #pragma unroll
    for (int rr = 0; rr < 4; ++rr)
        #pragma unroll
        for (int cc = 0; cc < 4; ++cc)
            op[(size_t)(i0 + rr*8 + ty)*384 + n0 + cc*8 + tx] = acc[rr][cc];
}

__global__ __launch_bounds__(256) void k_red(
    const float* __restrict__ outp, const float* __restrict__ bout,
    float* __restrict__ out)
{
    const int e = blockIdx.x * 256 + threadIdx.x;   // < 196608
    float v = bout[e % 384];
    #pragma unroll
    for (int q = 0; q < 6; ++q) v += outp[(size_t)q*196608 + e];
    out[e] = v;
}

// ---------------------------------------------------------------------------
extern "C" void kernel_launch(void* const* d_in, const int* in_sizes, int n_in,
                              void* d_out, int out_size, void* d_ws, size_t ws_size,
                              hipStream_t stream)
{
    const float* s      = (const float*)d_in[0];
    const float* z      = (const float*)d_in[1];
    const float* rots   = (const float*)d_in[2];
    const float* trans  = (const float*)d_in[3];
    const float* mask   = (const float*)d_in[4];
    const float* Wq     = (const float*)d_in[5];
    const float* bq     = (const float*)d_in[6];
    const float* Wkv    = (const float*)d_in[7];
    const float* bkv    = (const float*)d_in[8];
    const float* Wqp    = (const float*)d_in[9];
    const float* bqp    = (const float*)d_in[10];
    const float* Wkvp   = (const float*)d_in[11];
    const float* bkvp   = (const float*)d_in[12];
    const float* Wb     = (const float*)d_in[13];
    const float* bb     = (const float*)d_in[14];
    const float* head_w = (const float*)d_in[15];
    const float* Wout   = (const float*)d_in[16];
    const float* bout   = (const float*)d_in[17];
    float* out = (float*)d_out;

    float* ws    = (float*)d_ws;
    float* wcat  = ws;                      // 443520
    float* proj  = wcat  + 443520;          // 589824
    float* qp_g  = proj  + 589824;          // 73728
    float* kp_g  = qp_g  + 73728;           // 73728
    float* vp_g  = kp_g  + 73728;           // 147456
    float* abuf  = vp_g  + 147456;          // 3145728 (a; later aliased as outp)
    float* cat   = abuf  + 3145728;         // 1081344
    float* outp  = abuf;                    // 1179648 <= 3145728, abuf dead by k_outp

    k_wcat   <<<1733, 256, 0, stream>>>(Wq, bq, Wkv, bkv, Wqp, bqp, Wkvp, bkvp, wcat);
    k_proj   <<<dim3(16, 36), 64, 0, stream>>>(s, wcat, proj);
    k_rot    <<<512, 192, 0, stream>>>(proj, rots, trans, qp_g, kp_g, vp_g);
    k_logit  <<<dim3(512, 4), 256, 0, stream>>>(proj, z, mask, Wb, bb, head_w,
                                                qp_g, kp_g, abuf);
    k_softmax<<<1536, 256, 0, stream>>>(abuf);
    k_av     <<<256, 512, 0, stream>>>(abuf, proj, vp_g, rots, trans, cat);
    k_opair  <<<512, 512, 0, stream>>>(abuf, z, cat);
    k_outp   <<<dim3(16, 12, 6), 64, 0, stream>>>(cat, Wout, outp);
    k_red    <<<768, 256, 0, stream>>>(outp, bout, out);
}